// Round 7
// baseline (27.122 us; speedup 1.0000x reference)
//
#include <hip/hip_runtime.h>

// Problem constants (match reference):
//   B = 8192 batches, N = 64 antennas, K = 16 users, NOISE = 1.0
//   H: [B, N, K, 2] f32  (re/im interleaved, 32 floats per n-row)
//   P: [B, 2*N*K]  f32  (first N*K = Pr[n][j], second N*K = Pi[n][j])
// Output: scalar f32 = -(1/B) * sum_{b,k} log2(1 + sig/interf)
//
// R7: R6 showed the compiler won't keep 48 register-destined loads in
// flight (VGPR=36, latency-bound at all-pipes-idle). global_load_lds
// needs NO destination VGPRs -> stage P (8KB/batch) with 8 fire-and-forget
// DMA instructions, load H directly as 16 float2 (fills A-fragments),
// convert H while P flies, one vmcnt(0), then B-fragments via ds_read.
// Complex 16x16x64 matmul = 8 x mfma_f32_16x16x32_bf16. No atomics.
// C/D layout col=lane&15, row=4*(lane>>4)+reg (m89-verified).

typedef short bf16x8 __attribute__((ext_vector_type(8)));
typedef float f32x4  __attribute__((ext_vector_type(4)));
typedef int   i32x4  __attribute__((ext_vector_type(4)));

__device__ __forceinline__ int pk2(float lo, float hi) {
    int r;
    asm("v_cvt_pk_bf16_f32 %0, %1, %2" : "=v"(r) : "v"(lo), "v"(hi));
    return r;   // bf16(lo) low 16b, bf16(hi) high 16b (RNE)
}

__device__ __forceinline__ bf16x8 mk8(const float* v) {  // v[8] -> packed bf16 frag
    i32x4 t;
    #pragma unroll
    for (int i = 0; i < 4; ++i) t[i] = pk2(v[2 * i], v[2 * i + 1]);
    return __builtin_bit_cast(bf16x8, t);
}

__device__ __forceinline__ bf16x8 negbf(bf16x8 a) {      // flip all 8 sign bits
    i32x4 t = __builtin_bit_cast(i32x4, a);
    #pragma unroll
    for (int i = 0; i < 4; ++i) t[i] ^= 0x80008000;
    return __builtin_bit_cast(bf16x8, t);
}

__device__ __forceinline__ void gload16(const float* g, float* s) {
    __builtin_amdgcn_global_load_lds(
        (const __attribute__((address_space(1))) void*)g,
        (__attribute__((address_space(3))) void*)s,
        16, 0, 0);
}

#define MFMA __builtin_amdgcn_mfma_f32_16x16x32_bf16

__global__ __launch_bounds__(256, 4) void sumrate_kernel(
        const float* __restrict__ H, const float* __restrict__ P,
        float* __restrict__ ws) {
    __shared__ float sP[4 * 2048];            // 4 waves x 8KB P staging
    __shared__ float sRate[4];

    const int wave = threadIdx.x >> 6;        // 4 waves/block, 1 batch each
    const int lane = threadIdx.x & 63;
    const int b    = blockIdx.x * 4 + wave;
    const int j    = lane & 15;               // A row (k) and B col (j)
    const int g    = lane >> 4;               // n-slice group 0..3
    const int n0   = g * 8;                   // this lane's base n

    const float* gP = P + (size_t)b * 2048;   // 8KB: pr[1024] then pi[1024]
    const float* hA = H + (size_t)b * 2048 + n0 * 32 + 2 * j;
    float* sPw = sP + wave * 2048;

    // ---- P staging: 8 fire-and-forget 1KB DMA loads (zero VGPR cost) ----
    #pragma unroll
    for (int i = 0; i < 8; ++i)
        gload16(gP + i * 256 + lane * 4, sPw + i * 256);

    // ---- H direct loads: 16 x float2, coalesced, all in flight ----
    float2 h0[8], h1[8];                      // n 0..31 / 32..63 halves
    #pragma unroll
    for (int r = 0; r < 8; ++r) {
        h0[r] = *reinterpret_cast<const float2*>(hA + r * 32);
        h1[r] = *reinterpret_cast<const float2*>(hA + 1024 + r * 32);
    }
    __builtin_amdgcn_sched_barrier(0);        // keep loads above converts

    // ---- Convert H -> A fragments while P DMA is in flight ----
    float ar0[8], ai0[8], ar1[8], ai1[8];
    #pragma unroll
    for (int r = 0; r < 8; ++r) {
        ar0[r] = h0[r].x; ai0[r] = h0[r].y;
        ar1[r] = h1[r].x; ai1[r] = h1[r].y;
    }
    const bf16x8 Ahr0 = mk8(ar0), Ahr1 = mk8(ar1);
    const bf16x8 Ahi0 = mk8(ai0), Ahi1 = mk8(ai1);

    // ---- Drain DMA, read B fragments from LDS ----
    asm volatile("s_waitcnt vmcnt(0)" ::: "memory");
    __builtin_amdgcn_sched_barrier(0);

    float pr0[8], pr1[8], pi0[8], pi1[8];
    #pragma unroll
    for (int r = 0; r < 8; ++r) {
        pr0[r] = sPw[(n0 + r) * 16 + j];             // Pr[n0+r][j]
        pr1[r] = sPw[(n0 + r + 32) * 16 + j];
        pi0[r] = sPw[1024 + (n0 + r) * 16 + j];      // Pi[n0+r][j]
        pi1[r] = sPw[1024 + (n0 + r + 32) * 16 + j];
    }
    const bf16x8 Bpr0 = mk8(pr0), Bpr1 = mk8(pr1);
    const bf16x8 Bpi0 = mk8(pi0), Bpi1 = mk8(pi1);

    // ---- Complex 16x16x64 matmul: Dr = HrPr - HiPi, Di = HrPi + HiPr ----
    f32x4 dr = {0.f, 0.f, 0.f, 0.f}, di = {0.f, 0.f, 0.f, 0.f};
    dr = MFMA(Ahr0, Bpr0, dr, 0, 0, 0);
    dr = MFMA(Ahr1, Bpr1, dr, 0, 0, 0);
    dr = MFMA(negbf(Ahi0), Bpi0, dr, 0, 0, 0);
    dr = MFMA(negbf(Ahi1), Bpi1, dr, 0, 0, 0);
    di = MFMA(Ahr0, Bpi0, di, 0, 0, 0);
    di = MFMA(Ahr1, Bpi1, di, 0, 0, 0);
    di = MFMA(Ahi0, Bpr0, di, 0, 0, 0);
    di = MFMA(Ahi1, Bpr1, di, 0, 0, 0);

    // ---- Epilogue: C/D layout col=j=lane&15, row=k=4*g+reg ----
    float tot[4], sig[4];
    #pragma unroll
    for (int r = 0; r < 4; ++r) {
        const float mag = dr[r] * dr[r] + di[r] * di[r];
        const int k = g * 4 + r;
        tot[r] = mag;
        sig[r] = (j == k) ? mag : 0.0f;
    }
    // Row-sum over j: reduce across the 16 lanes of this g-group.
    #pragma unroll
    for (int m = 1; m < 16; m <<= 1) {
        #pragma unroll
        for (int r = 0; r < 4; ++r) {
            tot[r] += __shfl_xor(tot[r], m, 64);
            sig[r] += __shfl_xor(sig[r], m, 64);
        }
    }
    float rate = 0.0f;
    #pragma unroll
    for (int r = 0; r < 4; ++r)
        rate += log2f(1.0f + sig[r] / (tot[r] - sig[r] + 1.0f));
    // Sum the 4 groups (lane bits 4..5).
    rate += __shfl_xor(rate, 16, 64);
    rate += __shfl_xor(rate, 32, 64);

    // Combine the block's 4 per-batch rates -> one store per block.
    if (lane == 0) sRate[wave] = rate;
    __syncthreads();
    if (threadIdx.x == 0)
        ws[blockIdx.x] = sRate[0] + sRate[1] + sRate[2] + sRate[3];
}

// One block reduces the 2048 per-block rates and writes the scalar loss.
__global__ __launch_bounds__(1024) void reduce_kernel(
        const float* __restrict__ ws, float* __restrict__ out) {
    __shared__ float sPart[16];
    float s = ws[threadIdx.x] + ws[threadIdx.x + 1024];

    #pragma unroll
    for (int m = 1; m < 64; m <<= 1)
        s += __shfl_xor(s, m, 64);

    const int w = threadIdx.x >> 6;
    const int l = threadIdx.x & 63;
    if (l == 0) sPart[w] = s;
    __syncthreads();

    if (w == 0) {
        float t = (l < 16) ? sPart[l] : 0.0f;
        #pragma unroll
        for (int m = 1; m < 16; m <<= 1)
            t += __shfl_xor(t, m, 64);
        if (l == 0) out[0] = t * (-1.0f / 8192.0f);
    }
}

extern "C" void kernel_launch(void* const* d_in, const int* in_sizes, int n_in,
                              void* d_out, int out_size, void* d_ws, size_t ws_size,
                              hipStream_t stream) {
    const float* H = (const float*)d_in[0];
    const float* P = (const float*)d_in[1];
    float* out = (float*)d_out;
    float* ws  = (float*)d_ws;   // 2048 floats of per-block rate sums

    // 8192 batches, 1 wave per batch, 4 waves (batches) per 256-thread block
    sumrate_kernel<<<8192 / 4, 256, 0, stream>>>(H, P, ws);
    reduce_kernel<<<1, 1024, 0, stream>>>(ws, out);
}